// Round 2
// baseline (8169.545 us; speedup 1.0000x reference)
//
#include <hip/hip_runtime.h>

#define NSTEP 16

typedef __attribute__((ext_vector_type(8))) short s16x8;
typedef __attribute__((ext_vector_type(4))) float f32x4;

__device__ __forceinline__ float bf2f(unsigned short u){
  union { unsigned int i; float f; } v; v.i = ((unsigned int)u) << 16; return v.f;
}
__device__ __forceinline__ unsigned short f2bf(float f){
  union { float f; unsigned int i; } v; v.f = f;
  unsigned int r = v.i + 0x7fffu + ((v.i >> 16) & 1u);
  return (unsigned short)(r >> 16);
}
__device__ __forceinline__ float fast_rcp(float x){ return __builtin_amdgcn_rcpf(x); }
__device__ __forceinline__ float fast_tanh(float x){
  float e = __expf(2.0f * x);
  return 1.0f - 2.0f * fast_rcp(e + 1.0f);
}
__device__ __forceinline__ float fast_sigmoid(float x){
  return fast_rcp(1.0f + __expf(-x));
}
__device__ __forceinline__ void gload16(const void* g, void* l){
  __builtin_amdgcn_global_load_lds((const __attribute__((address_space(1))) void*)g,
                                   (__attribute__((address_space(3))) void*)l, 16, 0, 0);
}
__device__ __forceinline__ float wave_sum(float v){
#pragma unroll
  for (int off = 32; off; off >>= 1) v += __shfl_xor(v, off, 64);
  return v;
}
__device__ __forceinline__ float wave_max(float v){
#pragma unroll
  for (int off = 32; off; off >>= 1) v = fmaxf(v, __shfl_xor(v, off, 64));
  return v;
}

union LDSU {
  struct { unsigned short A[64 * 64]; unsigned short B[128 * 64]; } g;   // 24 KB
  struct { float a[512]; float red[16]; float cred[8][512]; } at;        // ~18 KB
  unsigned short tr[64][72];                                             // 9 KB
};

// device-scope generation barrier; bar[0]=count, bar[1]=generation
__device__ __forceinline__ void gridbar(int* bar){
  __syncthreads();
  if (threadIdx.x == 0){
    __threadfence();
    int old = __hip_atomic_load(&bar[1], __ATOMIC_RELAXED, __HIP_MEMORY_SCOPE_AGENT);
    int v = __hip_atomic_fetch_add(&bar[0], 1, __ATOMIC_ACQ_REL, __HIP_MEMORY_SCOPE_AGENT);
    if (v == (int)gridDim.x - 1){
      __hip_atomic_store(&bar[0], 0, __ATOMIC_RELAXED, __HIP_MEMORY_SCOPE_AGENT);
      __hip_atomic_store(&bar[1], old + 1, __ATOMIC_RELEASE, __HIP_MEMORY_SCOPE_AGENT);
    } else {
      while (__hip_atomic_load(&bar[1], __ATOMIC_ACQUIRE, __HIP_MEMORY_SCOPE_AGENT) == old)
        __builtin_amdgcn_s_sleep(1);
    }
    __threadfence();
  }
  __syncthreads();
}

// ---- 64x128 tile GEMM (K=512, BK=64), 512 threads = 8 waves (2x4 of 32x32) ----
// A: bf16 row-major MxK (or, EPI==3: A = Af0+Af1, f32, converted on stage)
// Bt: bf16 NxK row-major. XOR-swizzled LDS (16B chunk ^ (row&7)).
template<int EPI>
__device__ void gemm_tile(int mt, int nt,
    const unsigned short* A, const float* Af0, const float* Af1,
    const unsigned short* Bt,
    unsigned short* ob0, float* o0, float* o1,
    const float* e0, const float* e1, const float* e2, const float* e3,
    LDSU& lds){
  const int tid = threadIdx.x;
  const int lane = tid & 63, wid = tid >> 6;
  const int wr = wid >> 2, wc = wid & 3;
  unsigned short* ldsA = lds.g.A;
  unsigned short* ldsB = lds.g.B;
  f32x4 acc[2][2];
#pragma unroll
  for (int m = 0; m < 2; ++m)
#pragma unroll
    for (int n = 0; n < 2; ++n) acc[m][n] = (f32x4)0.0f;

  for (int kt = 0; kt < 512; kt += 64){
    __syncthreads();
    {
      int row = tid >> 3, kc = (tid & 7) ^ (row & 7);
      if constexpr (EPI == 3){
        const float* p0 = Af0 + (size_t)(mt * 64 + row) * 512 + kt + kc * 8;
        const float* p1 = Af1 + (size_t)(mt * 64 + row) * 512 + kt + kc * 8;
        float4 a0 = *(const float4*)p0, a1 = *(const float4*)(p0 + 4);
        float4 b0 = *(const float4*)p1, b1 = *(const float4*)(p1 + 4);
        s16x8 t8;
        t8[0] = (short)f2bf(a0.x + b0.x); t8[1] = (short)f2bf(a0.y + b0.y);
        t8[2] = (short)f2bf(a0.z + b0.z); t8[3] = (short)f2bf(a0.w + b0.w);
        t8[4] = (short)f2bf(a1.x + b1.x); t8[5] = (short)f2bf(a1.y + b1.y);
        t8[6] = (short)f2bf(a1.z + b1.z); t8[7] = (short)f2bf(a1.w + b1.w);
        *(s16x8*)&ldsA[tid * 8] = t8;
      } else {
        gload16(A + (size_t)(mt * 64 + row) * 512 + kt + kc * 8, &ldsA[tid * 8]);
      }
#pragma unroll
      for (int p = 0; p < 2; ++p){
        int s = p * 512 + tid;
        int br = s >> 3, bkc = (s & 7) ^ (br & 7);
        gload16(Bt + (size_t)(nt * 128 + br) * 512 + kt + bkc * 8, &ldsB[s * 8]);
      }
    }
    __syncthreads();
#pragma unroll
    for (int ks = 0; ks < 2; ++ks){
      int kc_l = (lane >> 4) + ks * 4;
      s16x8 av[2], bv[2];
#pragma unroll
      for (int m = 0; m < 2; ++m){
        int r = wr * 32 + m * 16 + (lane & 15);
        av[m] = *(const s16x8*)&ldsA[r * 64 + ((kc_l ^ (r & 7)) << 3)];
      }
#pragma unroll
      for (int n = 0; n < 2; ++n){
        int c = wc * 32 + n * 16 + (lane & 15);
        bv[n] = *(const s16x8*)&ldsB[c * 64 + ((kc_l ^ (c & 7)) << 3)];
      }
#pragma unroll
      for (int m = 0; m < 2; ++m)
#pragma unroll
        for (int n = 0; n < 2; ++n)
          acc[m][n] = __builtin_amdgcn_mfma_f32_16x16x32_bf16(av[m], bv[n], acc[m][n], 0, 0, 0);
    }
  }

#pragma unroll
  for (int m = 0; m < 2; ++m){
#pragma unroll
    for (int n = 0; n < 2; ++n){
      int r_base = mt * 64 + wr * 32 + m * 16 + ((lane >> 4) << 2);
      int col = nt * 128 + wc * 32 + n * 16 + (lane & 15);
#pragma unroll
      for (int q = 0; q < 4; ++q){
        float v = acc[m][n][q];
        size_t r_ = (size_t)(r_base + q);
        if constexpr (EPI == 0){
          ob0[r_ * 512 + col] = f2bf(v);
        } else if constexpr (EPI == 1){
          float t = fast_tanh(v);
          o0[r_ * 512 + col] = t;
          ob0[r_ * 512 + col] = f2bf(t);
        } else if constexpr (EPI == 2){
          o0[r_ * 1536 + col] = v;
        } else if constexpr (EPI == 3){
          float op = 0.f;
          const float* wo = e1 + (size_t)col * 12;
          const float* ob = e0 + r_ * 12;
#pragma unroll
          for (int o = 0; o < 12; ++o) op += ob[o] * wo[o];
          float v2 = v + op;
          if (col < 1024) v2 += e3[r_ * 1536 + 512 + col];    // + s@{ur,uz}
          if (col < 512){
            float rg = fast_sigmoid(v2);
            ob0[r_ * 512 + col] = f2bf(rg * e2[r_ * 512 + col]);   // rs bf16
          } else if (col < 1024){
            o0[r_ * 512 + (col - 512)] = fast_sigmoid(v2);         // z
          } else {
            o1[r_ * 512 + (col - 1024)] = v2;                      // c@c0+out@w0
          }
        } else if constexpr (EPI == 4){
          float v2 = v + e0[r_ * 512 + col];
          float sh = fast_tanh(v2);
          float z  = e1[r_ * 512 + col];
          float so = o0[r_ * 512 + col];
          float sn = (1.0f - z) * so + z * sh;
          o0[r_ * 512 + col] = sn;
          ob0[r_ * 512 + col] = f2bf(sn);
        }
      }
    }
  }
}

__device__ __forceinline__ void out_fc(int w, int lane, int step,
    const float* s_f32, const float* fcwT, const float* fcb,
    float* outb, float* dout){
  int b = w / 12, o = w - b * 12;
  const float* sp = s_f32 + (size_t)b * 512 + lane * 8;
  const float* fp = fcwT + (size_t)o * 512 + lane * 8;
  float4 sa = *(const float4*)sp, sb = *(const float4*)(sp + 4);
  float4 fa = *(const float4*)fp, fb = *(const float4*)(fp + 4);
  float sum = sa.x * fa.x + sa.y * fa.y + sa.z * fa.z + sa.w * fa.w +
              sb.x * fb.x + sb.y * fb.y + sb.z * fb.z + sb.w * fb.w;
  sum = wave_sum(sum);
  if (lane == 0){
    float v = sum + fcb[o];
    outb[b * 12 + o] = v;
    dout[(size_t)b * (NSTEP * 12) + step * 12 + o] = v;
  }
}

__global__ void barinit_k(int* bar){ bar[0] = 0; bar[1] = 0; }

__global__ __launch_bounds__(512, 2) void persist_k(
    const float* __restrict__ x,  const float* __restrict__ w0,
    const float* __restrict__ wz, const float* __restrict__ wrm,
    const float* __restrict__ wsm,const float* __restrict__ wa,
    const float* __restrict__ ua, const float* __restrict__ va,
    const float* __restrict__ u0, const float* __restrict__ uz,
    const float* __restrict__ urm,const float* __restrict__ c0,
    const float* __restrict__ cz, const float* __restrict__ cr,
    const float* __restrict__ fcw,const float* __restrict__ fcb,
    float* __restrict__ dout,
    unsigned short* xb, unsigned short* U, unsigned short* Pua,
    unsigned short* Pws, unsigned short* P1w, unsigned short* P2w,
    unsigned short* P3w, float* Wo2, float* fcwT, float* pre1,
    float* e_bt, float* c_part, unsigned short* rsb, float* zbuf,
    float* cu0, float* s_f32, unsigned short* s_bf, float* outb, int* bar){
  __shared__ LDSU lds;
  const int bid = blockIdx.x, tid = threadIdx.x;
  const int lane = tid & 63, wid = tid >> 6;

  // ---------- Ph0: cast x -> bf16; transpose weights ----------
  for (int it = 0; it < 32; ++it){
    size_t i8 = (size_t)it * 131072 + (size_t)bid * 512 + tid;
    const float* p = x + i8 * 8;
    float4 a = *(const float4*)p, b = *(const float4*)(p + 4);
    s16x8 t8;
    t8[0] = (short)f2bf(a.x); t8[1] = (short)f2bf(a.y);
    t8[2] = (short)f2bf(a.z); t8[3] = (short)f2bf(a.w);
    t8[4] = (short)f2bf(b.x); t8[5] = (short)f2bf(b.y);
    t8[6] = (short)f2bf(b.z); t8[7] = (short)f2bf(b.w);
    *(s16x8*)(xb + i8 * 8) = t8;
  }
  // 9 square 512x512 transposes, tiled 64x64 via LDS
  for (int tt = bid; tt < 576; tt += 256){
    int mi = tt >> 6, tile = tt & 63;
    int tr = tile >> 3, tc = tile & 7;
    const float* src; unsigned short* dst;
    switch (mi){
      case 0: src = ua;  dst = Pua;              break;
      case 1: src = wsm; dst = Pws;              break;
      case 2: src = wa;  dst = P1w;              break;
      case 3: src = urm; dst = P1w + 512 * 512;  break;
      case 4: src = uz;  dst = P1w + 1024 * 512; break;
      case 5: src = cr;  dst = P2w;              break;
      case 6: src = cz;  dst = P2w + 512 * 512;  break;
      case 7: src = c0;  dst = P2w + 1024 * 512; break;
      default:src = u0;  dst = P3w;              break;
    }
    __syncthreads();
    int r = tid >> 3, c8 = (tid & 7) * 8;
    const float* sp = src + (size_t)(tr * 64 + r) * 512 + tc * 64 + c8;
    float4 a = *(const float4*)sp, b = *(const float4*)(sp + 4);
    unsigned short* lp = &lds.tr[r][c8];
    lp[0] = f2bf(a.x); lp[1] = f2bf(a.y); lp[2] = f2bf(a.z); lp[3] = f2bf(a.w);
    lp[4] = f2bf(b.x); lp[5] = f2bf(b.y); lp[6] = f2bf(b.z); lp[7] = f2bf(b.w);
    __syncthreads();
    s16x8 o8;
#pragma unroll
    for (int k = 0; k < 8; ++k) o8[k] = (short)lds.tr[c8 + k][r];
    *(s16x8*)(dst + (size_t)(tc * 64 + r) * 512 + tr * 64 + c8) = o8;
  }
  // small transposes: Wo2[(p*512+h)*12+o], fcwT[o*512+h]
  {
    int gidx = bid * 512 + tid;
    if (gidx < 3 * 6144){
      int p = gidx / 6144, e = gidx % 6144;
      int o = e >> 9, h = e & 511;
      const float* w_ = (p == 0) ? wrm : (p == 1) ? wz : w0;
      Wo2[(size_t)(p * 512 + h) * 12 + o] = w_[o * 512 + h];
    } else if (gidx < 4 * 6144){
      int e = gidx - 3 * 6144;
      int h = e / 12, o = e - h * 12;
      fcwT[(size_t)o * 512 + h] = fcw[h * 12 + o];
    }
  }
  gridbar(bar);

  // ---------- Ph1: U = x@ua (bf16), s0 = tanh(x0@ws) ----------
  for (int tt = bid; tt < 4104; tt += 256){
    if (tt < 4096){
      gemm_tile<0>(tt >> 2, tt & 3, xb, nullptr, nullptr, Pua,
                   U, nullptr, nullptr, nullptr, nullptr, nullptr, nullptr, lds);
    } else {
      int q = tt - 4096;
      gemm_tile<1>(q >> 2, q & 3, xb, nullptr, nullptr, Pws,
                   s_bf, s_f32, nullptr, nullptr, nullptr, nullptr, nullptr, lds);
    }
  }
  gridbar(bar);

  // ---------- recurrence ----------
  for (int step = 1; step < NSTEP; ++step){
    // P1: pre1 = s@[wa|ur|uz]  (24 blocks)  ||  out-FC of s_{step-1} (192 blocks)
    if (bid < 24){
      gemm_tile<2>(bid / 12, bid % 12, s_bf, nullptr, nullptr, P1w,
                   nullptr, pre1, nullptr, nullptr, nullptr, nullptr, nullptr, lds);
    } else if (bid < 216){
      out_fc((bid - 24) * 8 + wid, lane, step - 1, s_f32, fcwT, fcb, outb, dout);
    }
    gridbar(bar);

    // P2a: e[b][t] = sum_h tanh(pre1_wa + U) * va
    {
      int b = bid >> 1, j = bid & 1;
      const float* pp = pre1 + (size_t)b * 1536 + lane * 8;
      float4 s0v = *(const float4*)pp, s1v = *(const float4*)(pp + 4);
      const float* vp = va + lane * 8;
      float4 v0 = *(const float4*)vp, v1 = *(const float4*)(vp + 4);
      float sv[8] = {s0v.x, s0v.y, s0v.z, s0v.w, s1v.x, s1v.y, s1v.z, s1v.w};
      float vv[8] = {v0.x, v0.y, v0.z, v0.w, v1.x, v1.y, v1.z, v1.w};
      int t0 = j * 256 + wid * 32;
      for (int tt2 = 0; tt2 < 32; ++tt2){
        int t = t0 + tt2;
        s16x8 uv = *(const s16x8*)(U + ((size_t)t * 128 + b) * 512 + lane * 8);
        float sum = 0.f;
#pragma unroll
        for (int k = 0; k < 8; ++k)
          sum += fast_tanh(bf2f((unsigned short)uv[k]) + sv[k]) * vv[k];
        sum = wave_sum(sum);
        if (lane == 0) e_bt[(size_t)b * 512 + t] = sum;
      }
    }
    gridbar(bar);

    // P2b: softmax over t (block-local, redundant per pair) + partial c
    {
      int b = bid >> 1, j = bid & 1;
      float e = e_bt[(size_t)b * 512 + tid];
      float m = wave_max(e);
      if (lane == 0) lds.at.red[wid] = m;
      __syncthreads();
      m = lds.at.red[0];
#pragma unroll
      for (int w = 1; w < 8; ++w) m = fmaxf(m, lds.at.red[w]);
      float p = __expf(e - m);
      float s = wave_sum(p);
      if (lane == 0) lds.at.red[8 + wid] = s;
      __syncthreads();
      float den = 0.f;
#pragma unroll
      for (int w = 0; w < 8; ++w) den += lds.at.red[8 + w];
      lds.at.a[tid] = p * fast_rcp(den);
      __syncthreads();
      float acc[8] = {0, 0, 0, 0, 0, 0, 0, 0};
      int t0 = j * 256 + wid * 32;
      for (int tt2 = 0; tt2 < 32; ++tt2){
        int t = t0 + tt2;
        float a = lds.at.a[t];
        s16x8 xv = *(const s16x8*)(xb + ((size_t)t * 128 + b) * 512 + lane * 8);
#pragma unroll
        for (int k = 0; k < 8; ++k) acc[k] += a * bf2f((unsigned short)xv[k]);
      }
#pragma unroll
      for (int k = 0; k < 8; ++k) lds.at.cred[wid][lane * 8 + k] = acc[k];
      __syncthreads();
      float cs = 0.f;
#pragma unroll
      for (int w = 0; w < 8; ++w) cs += lds.at.cred[w][tid];
      c_part[((size_t)j * 128 + b) * 512 + tid] = cs;
    }
    gridbar(bar);

    // P3: gates = c@[cr|cz|c0] + out@W (+ s@{ur,uz})  (24 blocks)
    if (bid < 24){
      gemm_tile<3>(bid / 12, bid % 12, nullptr, c_part, c_part + 128 * 512, P2w,
                   rsb, zbuf, cu0, outb, Wo2, s_f32, pre1, lds);
    }
    gridbar(bar);

    // P4: sh = tanh(cu0 + (r*s)@u0); s = (1-z)s + z*sh  (8 blocks)
    if (bid < 8){
      gemm_tile<4>(bid / 4, bid & 3, rsb, nullptr, nullptr, P3w,
                   s_bf, s_f32, nullptr, cu0, zbuf, nullptr, nullptr, lds);
    }
    gridbar(bar);
  }

  // final out-FC for step 15
  if (bid < 192){
    out_fc(bid * 8 + wid, lane, NSTEP - 1, s_f32, fcwT, fcb, outb, dout);
  }
}

// ---------------- host launch ----------------
extern "C" void kernel_launch(void* const* d_in, const int* in_sizes, int n_in,
                              void* d_out, int out_size, void* d_ws, size_t ws_size,
                              hipStream_t stream){
  const float* x   = (const float*)d_in[0];
  const float* w0  = (const float*)d_in[1];
  const float* wz  = (const float*)d_in[2];
  const float* wrm = (const float*)d_in[3];
  const float* wsm = (const float*)d_in[4];
  const float* wa  = (const float*)d_in[5];
  const float* ua  = (const float*)d_in[6];
  const float* va  = (const float*)d_in[7];
  const float* u0  = (const float*)d_in[8];
  const float* uz  = (const float*)d_in[9];
  const float* urm = (const float*)d_in[10];
  const float* c0  = (const float*)d_in[11];
  const float* cz  = (const float*)d_in[12];
  const float* cr  = (const float*)d_in[13];
  const float* fcw = (const float*)d_in[14];
  const float* fcb = (const float*)d_in[15];
  float* dout = (float*)d_out;

  char* base = (char*)d_ws;
  size_t off = 0;
  auto alloc = [&](size_t bytes) -> char* {
    char* p = base + off; off += (bytes + 255) & ~(size_t)255; return p;
  };
  unsigned short* xb   = (unsigned short*)alloc((size_t)512 * 128 * 512 * 2);
  unsigned short* U    = (unsigned short*)alloc((size_t)512 * 128 * 512 * 2);
  unsigned short* Pua  = (unsigned short*)alloc(512 * 512 * 2);
  unsigned short* Pws  = (unsigned short*)alloc(512 * 512 * 2);
  unsigned short* P1w  = (unsigned short*)alloc((size_t)1536 * 512 * 2);
  unsigned short* P2w  = (unsigned short*)alloc((size_t)1536 * 512 * 2);
  unsigned short* P3w  = (unsigned short*)alloc(512 * 512 * 2);
  float* Wo2           = (float*)alloc(1536 * 12 * 4);
  float* fcwT          = (float*)alloc(12 * 512 * 4);
  float* pre1          = (float*)alloc((size_t)128 * 1536 * 4);
  float* e_bt          = (float*)alloc((size_t)128 * 512 * 4);
  float* c_part        = (float*)alloc((size_t)2 * 128 * 512 * 4);
  unsigned short* rsb  = (unsigned short*)alloc((size_t)128 * 512 * 2);
  float* zbuf          = (float*)alloc((size_t)128 * 512 * 4);
  float* cu0           = (float*)alloc((size_t)128 * 512 * 4);
  float* s_f32         = (float*)alloc((size_t)128 * 512 * 4);
  unsigned short* s_bf = (unsigned short*)alloc((size_t)128 * 512 * 2);
  float* outb          = (float*)alloc(128 * 12 * 4);
  int* bar             = (int*)alloc(256);
  (void)ws_size; (void)in_sizes; (void)n_in; (void)out_size;

  barinit_k<<<1, 1, 0, stream>>>(bar);
  persist_k<<<256, 512, 0, stream>>>(
      x, w0, wz, wrm, wsm, wa, ua, va, u0, uz, urm, c0, cz, cr, fcw, fcb,
      dout, xb, U, Pua, Pws, P1w, P2w, P3w, Wo2, fcwT, pre1, e_bt, c_part,
      rsb, zbuf, cu0, s_f32, s_bf, outb, bar);
}

// Round 3
// 1083.391 us; speedup vs baseline: 7.5407x; 7.5407x over previous
//
#include <hip/hip_runtime.h>

#define NSTEP 16

typedef __attribute__((ext_vector_type(8))) short s16x8;
typedef __attribute__((ext_vector_type(4))) float f32x4;

__device__ __forceinline__ float bf2f(unsigned short u){
  union { unsigned int i; float f; } v; v.i = ((unsigned int)u) << 16; return v.f;
}
__device__ __forceinline__ unsigned short f2bf(float f){
  union { float f; unsigned int i; } v; v.f = f;
  unsigned int r = v.i + 0x7fffu + ((v.i >> 16) & 1u);
  return (unsigned short)(r >> 16);
}
__device__ __forceinline__ float fast_rcp(float x){ return __builtin_amdgcn_rcpf(x); }
__device__ __forceinline__ float fast_tanh(float x){
  float e = __expf(2.0f * x);
  return 1.0f - 2.0f * fast_rcp(e + 1.0f);
}
__device__ __forceinline__ float fast_sigmoid(float x){
  return fast_rcp(1.0f + __expf(-x));
}
__device__ __forceinline__ void gload16(const void* g, void* l){
  __builtin_amdgcn_global_load_lds((const __attribute__((address_space(1))) void*)g,
                                   (__attribute__((address_space(3))) void*)l, 16, 0, 0);
}
__device__ __forceinline__ float wave_sum(float v){
#pragma unroll
  for (int off = 32; off; off >>= 1) v += __shfl_xor(v, off, 64);
  return v;
}
__device__ __forceinline__ float wave_max(float v){
#pragma unroll
  for (int off = 32; off; off >>= 1) v = fmaxf(v, __shfl_xor(v, off, 64));
  return v;
}

struct GemmLDS { unsigned short A[64 * 64]; unsigned short B[128 * 64]; };

// ---- 64x128 tile GEMM body (K=512, BK=64), 512 threads, 8 waves (2x4 of 32x32)
// A: bf16 MxK row-major; Bt: bf16 NxK row-major. XOR-swizzled LDS.
template<int EPI>
__device__ __forceinline__ void gemm_body(int mt, int nt,
    const unsigned short* __restrict__ A, const unsigned short* __restrict__ Bt,
    unsigned short* __restrict__ ob0, float* __restrict__ o0, float* __restrict__ o1,
    const float* __restrict__ e0, const float* __restrict__ e1,
    const float* __restrict__ e2, const float* __restrict__ e3,
    GemmLDS& lds){
  const int tid = threadIdx.x;
  const int lane = tid & 63, wid = tid >> 6;
  const int wr = wid >> 2, wc = wid & 3;
  f32x4 acc[2][2];
#pragma unroll
  for (int m = 0; m < 2; ++m)
#pragma unroll
    for (int n = 0; n < 2; ++n) acc[m][n] = (f32x4)0.0f;

  for (int kt = 0; kt < 512; kt += 64){
    __syncthreads();
    {
      int row = tid >> 3, kc = (tid & 7) ^ (row & 7);
      gload16(A + (size_t)(mt * 64 + row) * 512 + kt + kc * 8, &lds.A[tid * 8]);
#pragma unroll
      for (int p = 0; p < 2; ++p){
        int s = p * 512 + tid;
        int br = s >> 3, bkc = (s & 7) ^ (br & 7);
        gload16(Bt + (size_t)(nt * 128 + br) * 512 + kt + bkc * 8, &lds.B[s * 8]);
      }
    }
    __syncthreads();
#pragma unroll
    for (int ks = 0; ks < 2; ++ks){
      int kc_l = (lane >> 4) + ks * 4;
      s16x8 av[2], bv[2];
#pragma unroll
      for (int m = 0; m < 2; ++m){
        int r = wr * 32 + m * 16 + (lane & 15);
        av[m] = *(const s16x8*)&lds.A[r * 64 + ((kc_l ^ (r & 7)) << 3)];
      }
#pragma unroll
      for (int n = 0; n < 2; ++n){
        int c = wc * 32 + n * 16 + (lane & 15);
        bv[n] = *(const s16x8*)&lds.B[c * 64 + ((kc_l ^ (c & 7)) << 3)];
      }
#pragma unroll
      for (int m = 0; m < 2; ++m)
#pragma unroll
        for (int n = 0; n < 2; ++n)
          acc[m][n] = __builtin_amdgcn_mfma_f32_16x16x32_bf16(av[m], bv[n], acc[m][n], 0, 0, 0);
    }
  }

#pragma unroll
  for (int m = 0; m < 2; ++m){
#pragma unroll
    for (int n = 0; n < 2; ++n){
      int r_base = mt * 64 + wr * 32 + m * 16 + ((lane >> 4) << 2);
      int col = nt * 128 + wc * 32 + n * 16 + (lane & 15);
#pragma unroll
      for (int q = 0; q < 4; ++q){
        float v = acc[m][n][q];
        size_t r_ = (size_t)(r_base + q);
        if constexpr (EPI == 0){
          ob0[r_ * 512 + col] = f2bf(v);
        } else if constexpr (EPI == 1){
          float t = fast_tanh(v);
          o0[r_ * 512 + col] = t;
          ob0[r_ * 512 + col] = f2bf(t);
        } else if constexpr (EPI == 2){
          o0[r_ * 1536 + col] = v;
        } else if constexpr (EPI == 3){
          // acc = c@[cr|cz|c0]; + out@W (e1=Wo2 [1536][12], e0=outb [b][12])
          float op = 0.f;
          const float* wo = e1 + (size_t)col * 12;
          const float* ob = e0 + r_ * 12;
#pragma unroll
          for (int o = 0; o < 12; ++o) op += ob[o] * wo[o];
          float v2 = v + op;
          if (col < 1024) v2 += e3[r_ * 1536 + 512 + col];    // + s@{ur,uz}
          if (col < 512){
            float rg = fast_sigmoid(v2);
            ob0[r_ * 512 + col] = f2bf(rg * e2[r_ * 512 + col]);   // rs (bf16)
          } else if (col < 1024){
            o0[r_ * 512 + (col - 512)] = fast_sigmoid(v2);         // z
          } else {
            o1[r_ * 512 + (col - 1024)] = v2;                      // c@c0+out@w0
          }
        } else if constexpr (EPI == 4){
          float v2 = v + e0[r_ * 512 + col];
          float sh = fast_tanh(v2);
          float z  = e1[r_ * 512 + col];
          float so = o0[r_ * 512 + col];
          float sn = (1.0f - z) * so + z * sh;
          o0[r_ * 512 + col] = sn;
          ob0[r_ * 512 + col] = f2bf(sn);
        }
      }
    }
  }
}

template<int EPI>
__global__ __launch_bounds__(512) void gemm_k(
    const unsigned short* __restrict__ A, const unsigned short* __restrict__ Bt,
    unsigned short* __restrict__ ob0, float* __restrict__ o0, float* __restrict__ o1,
    const float* __restrict__ e0, const float* __restrict__ e1,
    const float* __restrict__ e2, const float* __restrict__ e3){
  __shared__ GemmLDS lds;
  gemm_body<EPI>(blockIdx.y, blockIdx.x, A, Bt, ob0, o0, o1, e0, e1, e2, e3, lds);
}

__device__ __forceinline__ void out_fc(int w, int lane, int step,
    const float* __restrict__ s_f32, const float* __restrict__ fcwT,
    const float* __restrict__ fcb, float* __restrict__ outb, float* __restrict__ dout){
  int b = w / 12, o = w - b * 12;
  const float* sp = s_f32 + (size_t)b * 512 + lane * 8;
  const float* fp = fcwT + (size_t)o * 512 + lane * 8;
  float4 sa = *(const float4*)sp, sb = *(const float4*)(sp + 4);
  float4 fa = *(const float4*)fp, fb = *(const float4*)(fp + 4);
  float sum = sa.x * fa.x + sa.y * fa.y + sa.z * fa.z + sa.w * fa.w +
              sb.x * fb.x + sb.y * fb.y + sb.z * fb.z + sb.w * fb.w;
  sum = wave_sum(sum);
  if (lane == 0){
    float v = sum + fcb[o];
    outb[b * 12 + o] = v;
    dout[(size_t)b * (NSTEP * 12) + step * 12 + o] = v;
  }
}

// k1: blocks 0..23 -> pre1 = s@[wa|ur|uz]; blocks 24..215 -> out_fc(step-1)
__global__ __launch_bounds__(512) void step1_k(
    const unsigned short* __restrict__ s_bf, const unsigned short* __restrict__ P1w,
    float* __restrict__ pre1, const float* __restrict__ s_f32,
    const float* __restrict__ fcwT, const float* __restrict__ fcb,
    float* __restrict__ outb, float* __restrict__ dout, int prev_step){
  __shared__ GemmLDS lds;
  int bid = blockIdx.x;
  if (bid < 24){
    gemm_body<2>(bid / 12, bid % 12, s_bf, P1w, nullptr, pre1, nullptr,
                 nullptr, nullptr, nullptr, nullptr, lds);
  } else {
    int lane = threadIdx.x & 63, wid = threadIdx.x >> 6;
    out_fc((bid - 24) * 8 + wid, lane, prev_step, s_f32, fcwT, fcb, outb, dout);
  }
}

// e_k: grid (tchunk=8, b=128), 256 thr, wave = 16 t-rows
__global__ __launch_bounds__(256) void e_k(const unsigned short* __restrict__ U,
    const float* __restrict__ pre1, const float* __restrict__ va,
    float* __restrict__ e_bt){
  int b = blockIdx.y, tc = blockIdx.x;
  int lane = threadIdx.x & 63, wid = threadIdx.x >> 6;
  const float* pp = pre1 + (size_t)b * 1536 + lane * 8;
  float4 s0v = *(const float4*)pp, s1v = *(const float4*)(pp + 4);
  const float* vp = va + lane * 8;
  float4 v0 = *(const float4*)vp, v1 = *(const float4*)(vp + 4);
  float sv[8] = {s0v.x, s0v.y, s0v.z, s0v.w, s1v.x, s1v.y, s1v.z, s1v.w};
  float vv[8] = {v0.x, v0.y, v0.z, v0.w, v1.x, v1.y, v1.z, v1.w};
  int t0 = tc * 64 + wid * 16;
#pragma unroll 4
  for (int i = 0; i < 16; ++i){
    int t = t0 + i;
    s16x8 uv = *(const s16x8*)(U + ((size_t)t * 128 + b) * 512 + lane * 8);
    float sum = 0.f;
#pragma unroll
    for (int k = 0; k < 8; ++k)
      sum += fast_tanh(bf2f((unsigned short)uv[k]) + sv[k]) * vv[k];
    sum = wave_sum(sum);
    if (lane == 0) e_bt[(size_t)b * 512 + t] = sum;
  }
}

// c_k: grid (ic=4, b=128), 256 thr; block-local softmax + c over 128-col chunk
__global__ __launch_bounds__(256) void c_k(const unsigned short* __restrict__ xb,
    const float* __restrict__ e_bt, unsigned short* __restrict__ cbf){
  __shared__ float a_s[512];
  __shared__ float red[8];
  __shared__ float cred[4][128];
  int b = blockIdx.y, ic = blockIdx.x;
  int tid = threadIdx.x;
  int lane = tid & 63, wid = tid >> 6;
  // softmax over t (block-local, redundant across ic)
  float e0v = e_bt[(size_t)b * 512 + tid];
  float e1v = e_bt[(size_t)b * 512 + 256 + tid];
  float m = wave_max(fmaxf(e0v, e1v));
  if (lane == 0) red[wid] = m;
  __syncthreads();
  m = fmaxf(fmaxf(red[0], red[1]), fmaxf(red[2], red[3]));
  float p0 = __expf(e0v - m), p1 = __expf(e1v - m);
  float s = wave_sum(p0 + p1);
  if (lane == 0) red[4 + wid] = s;
  __syncthreads();
  float den = red[4] + red[5] + red[6] + red[7];
  float rden = fast_rcp(den);
  a_s[tid] = p0 * rden;
  a_s[tid + 256] = p1 * rden;
  __syncthreads();
  // c-pass: quarter-wave rows (16 lanes x 16B = 256B = 128 bf16)
  int lane16 = lane & 15, q4 = lane >> 4;
  float acc[8] = {0, 0, 0, 0, 0, 0, 0, 0};
  for (int round = 0; round < 32; ++round){
    int t = round * 16 + wid * 4 + q4;
    float a = a_s[t];
    s16x8 xv = *(const s16x8*)(xb + ((size_t)t * 128 + b) * 512 + ic * 128 + lane16 * 8);
#pragma unroll
    for (int k = 0; k < 8; ++k) acc[k] += a * bf2f((unsigned short)xv[k]);
  }
#pragma unroll
  for (int k = 0; k < 8; ++k){
    acc[k] += __shfl_xor(acc[k], 16, 64);
    acc[k] += __shfl_xor(acc[k], 32, 64);
  }
  if (q4 == 0){
#pragma unroll
    for (int k = 0; k < 8; ++k) cred[wid][lane16 * 8 + k] = acc[k];
  }
  __syncthreads();
  if (tid < 128){
    float cs = cred[0][tid] + cred[1][tid] + cred[2][tid] + cred[3][tid];
    cbf[(size_t)b * 512 + ic * 128 + tid] = f2bf(cs);
  }
}

// tail: out_fc for step 15
__global__ __launch_bounds__(512) void outtail_k(const float* __restrict__ s_f32,
    const float* __restrict__ fcwT, const float* __restrict__ fcb,
    float* __restrict__ outb, float* __restrict__ dout){
  int lane = threadIdx.x & 63, wid = threadIdx.x >> 6;
  out_fc(blockIdx.x * 8 + wid, lane, NSTEP - 1, s_f32, fcwT, fcb, outb, dout);
}

// ---------------- setup kernels ----------------
__global__ __launch_bounds__(256) void castx_k(const float* __restrict__ x,
                                               unsigned short* __restrict__ xb){
  size_t idx = (size_t)blockIdx.x * 256 + threadIdx.x;
  const float* p = x + idx * 8;
  float4 a = *(const float4*)p, b = *(const float4*)(p + 4);
  s16x8 t8;
  t8[0] = (short)f2bf(a.x); t8[1] = (short)f2bf(a.y);
  t8[2] = (short)f2bf(a.z); t8[3] = (short)f2bf(a.w);
  t8[4] = (short)f2bf(b.x); t8[5] = (short)f2bf(b.y);
  t8[6] = (short)f2bf(b.z); t8[7] = (short)f2bf(b.w);
  *(s16x8*)(xb + idx * 8) = t8;
}

// fused: 9 square 512x512 transposes (f32->bf16) + Wo2 + fcwT
__global__ __launch_bounds__(512) void trans_k(
    const float* __restrict__ ua, const float* __restrict__ wsm,
    const float* __restrict__ wa, const float* __restrict__ urm,
    const float* __restrict__ uz, const float* __restrict__ cr,
    const float* __restrict__ cz, const float* __restrict__ c0,
    const float* __restrict__ u0, const float* __restrict__ wrm,
    const float* __restrict__ wzm, const float* __restrict__ w0m,
    const float* __restrict__ fcw,
    unsigned short* __restrict__ Pua, unsigned short* __restrict__ Pws,
    unsigned short* __restrict__ P1w, unsigned short* __restrict__ P2w,
    unsigned short* __restrict__ P3w, float* __restrict__ Wo2,
    float* __restrict__ fcwT){
  __shared__ unsigned short tr[64][72];
  int bid = blockIdx.x, tid = threadIdx.x;
  if (bid < 576){
    int mi = bid >> 6, tile = bid & 63;
    int trr = tile >> 3, tcc = tile & 7;
    const float* src; unsigned short* dst;
    switch (mi){
      case 0: src = ua;  dst = Pua;              break;
      case 1: src = wsm; dst = Pws;              break;
      case 2: src = wa;  dst = P1w;              break;
      case 3: src = urm; dst = P1w + 512 * 512;  break;
      case 4: src = uz;  dst = P1w + 1024 * 512; break;
      case 5: src = cr;  dst = P2w;              break;
      case 6: src = cz;  dst = P2w + 512 * 512;  break;
      case 7: src = c0;  dst = P2w + 1024 * 512; break;
      default:src = u0;  dst = P3w;              break;
    }
    int r = tid >> 3, c8 = (tid & 7) * 8;
    const float* sp = src + (size_t)(trr * 64 + r) * 512 + tcc * 64 + c8;
    float4 a = *(const float4*)sp, b = *(const float4*)(sp + 4);
    unsigned short* lp = &tr[r][c8];
    lp[0] = f2bf(a.x); lp[1] = f2bf(a.y); lp[2] = f2bf(a.z); lp[3] = f2bf(a.w);
    lp[4] = f2bf(b.x); lp[5] = f2bf(b.y); lp[6] = f2bf(b.z); lp[7] = f2bf(b.w);
    __syncthreads();
    s16x8 o8;
#pragma unroll
    for (int k = 0; k < 8; ++k) o8[k] = (short)tr[c8 + k][r];
    *(s16x8*)(dst + (size_t)(tcc * 64 + r) * 512 + trr * 64 + c8) = o8;
  } else {
    int gidx = (bid - 576) * 512 + tid;
    if (gidx < 18432){
      int p = gidx / 6144, e = gidx % 6144;
      int o = e >> 9, h = e & 511;
      const float* w_ = (p == 0) ? wrm : (p == 1) ? wzm : w0m;
      Wo2[(size_t)(p * 512 + h) * 12 + o] = w_[o * 512 + h];
    } else if (gidx < 24576){
      int e = gidx - 18432;
      int h = e / 12, o = e - h * 12;
      fcwT[(size_t)o * 512 + h] = fcw[h * 12 + o];
    }
  }
}

// ---------------- host launch ----------------
extern "C" void kernel_launch(void* const* d_in, const int* in_sizes, int n_in,
                              void* d_out, int out_size, void* d_ws, size_t ws_size,
                              hipStream_t stream){
  const float* x   = (const float*)d_in[0];
  const float* w0  = (const float*)d_in[1];
  const float* wz  = (const float*)d_in[2];
  const float* wrm = (const float*)d_in[3];
  const float* wsm = (const float*)d_in[4];
  const float* wa  = (const float*)d_in[5];
  const float* ua  = (const float*)d_in[6];
  const float* va  = (const float*)d_in[7];
  const float* u0  = (const float*)d_in[8];
  const float* uz  = (const float*)d_in[9];
  const float* urm = (const float*)d_in[10];
  const float* c0  = (const float*)d_in[11];
  const float* cz  = (const float*)d_in[12];
  const float* cr  = (const float*)d_in[13];
  const float* fcw = (const float*)d_in[14];
  const float* fcb = (const float*)d_in[15];
  float* dout = (float*)d_out;

  char* base = (char*)d_ws;
  size_t off = 0;
  auto alloc = [&](size_t bytes) -> char* {
    char* p = base + off; off += (bytes + 255) & ~(size_t)255; return p;
  };
  unsigned short* xb   = (unsigned short*)alloc((size_t)512 * 128 * 512 * 2);
  unsigned short* U    = (unsigned short*)alloc((size_t)512 * 128 * 512 * 2);
  unsigned short* Pua  = (unsigned short*)alloc(512 * 512 * 2);
  unsigned short* Pws  = (unsigned short*)alloc(512 * 512 * 2);
  unsigned short* P1w  = (unsigned short*)alloc((size_t)1536 * 512 * 2);
  unsigned short* P2w  = (unsigned short*)alloc((size_t)1536 * 512 * 2);
  unsigned short* P3w  = (unsigned short*)alloc(512 * 512 * 2);
  float* Wo2           = (float*)alloc(1536 * 12 * 4);
  float* fcwT          = (float*)alloc(12 * 512 * 4);
  float* pre1          = (float*)alloc((size_t)128 * 1536 * 4);
  float* e_bt          = (float*)alloc((size_t)128 * 512 * 4);
  unsigned short* cbf  = (unsigned short*)alloc((size_t)128 * 512 * 2);
  unsigned short* rsb  = (unsigned short*)alloc((size_t)128 * 512 * 2);
  float* zbuf          = (float*)alloc((size_t)128 * 512 * 4);
  float* cu0           = (float*)alloc((size_t)128 * 512 * 4);
  float* s_f32         = (float*)alloc((size_t)128 * 512 * 4);
  unsigned short* s_bf = (unsigned short*)alloc((size_t)128 * 512 * 2);
  float* outb          = (float*)alloc(128 * 12 * 4);
  (void)ws_size; (void)in_sizes; (void)n_in; (void)out_size;

  // setup
  castx_k<<<16384, 256, 0, stream>>>(x, xb);
  trans_k<<<624, 512, 0, stream>>>(ua, wsm, wa, urm, uz, cr, cz, c0, u0,
                                   wrm, wz, w0, fcw,
                                   Pua, Pws, P1w, P2w, P3w, Wo2, fcwT);
  // U = x @ ua (bf16)
  gemm_k<0><<<dim3(4, 1024), 512, 0, stream>>>(xb, Pua, U, nullptr, nullptr,
                                               nullptr, nullptr, nullptr, nullptr);
  // s0 = tanh(x0 @ ws)
  gemm_k<1><<<dim3(4, 2), 512, 0, stream>>>(xb, Pws, s_bf, s_f32, nullptr,
                                            nullptr, nullptr, nullptr, nullptr);

  for (int step = 1; step < NSTEP; ++step){
    step1_k<<<216, 512, 0, stream>>>(s_bf, P1w, pre1, s_f32, fcwT, fcb,
                                     outb, dout, step - 1);
    e_k<<<dim3(8, 128), 256, 0, stream>>>(U, pre1, va, e_bt);
    c_k<<<dim3(4, 128), 256, 0, stream>>>(xb, e_bt, cbf);
    gemm_k<3><<<dim3(12, 2), 512, 0, stream>>>(cbf, P2w, rsb, zbuf, cu0,
                                               outb, Wo2, s_f32, pre1);
    gemm_k<4><<<dim3(4, 2), 512, 0, stream>>>(rsb, P3w, s_bf, s_f32, nullptr,
                                              cu0, zbuf, nullptr, nullptr);
  }
  outtail_k<<<192, 512, 0, stream>>>(s_f32, fcwT, fcb, outb, dout);
}